// Round 10
// baseline (245.158 us; speedup 1.0000x reference)
//
#include <hip/hip_runtime.h>
#include <hip/hip_bf16.h>
#include <math.h>

// HashMemory: B=8, S=4096, E=1024, Dm=512, M=64 slots.
// memory at step t == write_vals of tokens [t-64, t-1]  => window-64 attention.
// Pipeline: WVQ = emb(f32, cast fused) @ [W_write|W_query] (256^2 MFMA GEMM);
// WVT = WV^T (tiled transpose); windowed attention (MFMA QK^T + wave-local
// softmax + MFMA PV); out = R @ W_out (256^2 MFMA GEMM, f32 out).
// r10: compute loop mh-outer so A fragments are ds_read ONCE (32 vs 48
// b128/wave/tile, LDS was the bound); staging spread across tile body;
// single cheap vmcnt(0)+lgkmcnt(0)+barrier per K-tile.

#define BATCH   8
#define S_LEN   4096
#define EMB     1024
#define DM      512
#define MROWS   (BATCH * S_LEN)          // 32768
#define SCALE_F 0.04419417382415922f     // 512^-0.5

typedef __attribute__((ext_vector_type(4))) float f32x4;
typedef __attribute__((ext_vector_type(8))) short short8;

__device__ __forceinline__ unsigned short f2bf(float f) {
    __hip_bfloat16 h = __float2bfloat16(f);
    return *reinterpret_cast<unsigned short*>(&h);
}

// ---------------------------------------------------------------------------
__global__ __launch_bounds__(256) void tcast(const float* __restrict__ in,
                                             __hip_bfloat16* __restrict__ out,
                                             int K, int N)
{
    int id = blockIdx.x * 256 + threadIdx.x;
    if (id >= K * N) return;
    int n = id / K, k = id % K;
    out[id] = __float2bfloat16(in[k * N + n]);
}

__global__ __launch_bounds__(256) void concat_bias(const float* __restrict__ a,
                                                   const float* __restrict__ b,
                                                   float* __restrict__ out)
{
    int i = blockIdx.x * 256 + threadIdx.x;
    if (i < 512) out[i] = a[i];
    else if (i < 1024) out[i] = b[i - 512];
}

// ---------------------------------------------------------------------------
// bf16 MFMA GEMM, 256x256 tile: C[M x N] = A[M x K] @ Bt[N x K]^T + bias.
// 512 threads = 8 waves (2x4); per-wave output 128x64; BK=64.
// LDS: [buf][A 32K | B 32K] x2 = 128KB. Rows 128B, chunk swizzle ^(row&7).
// AF32: A read as f32, converted in-register during staging (fused cast).
// ---------------------------------------------------------------------------
template<bool BF16OUT, bool AF32>
__global__ __launch_bounds__(512, 2) void gemm256(
    const void* __restrict__ Av, int lda,
    const __hip_bfloat16* __restrict__ Bt, int ldb,
    const float* __restrict__ bias,
    void* __restrict__ Cv, int ldc,
    int K, int nbx)
{
    __shared__ __align__(16) char smem[131072];

    const int nwg = gridDim.x;
    const int bid = blockIdx.x;
    const int cpx = nwg >> 3;                    // nwg divisible by 8
    const int swz = (bid & 7) * cpx + (bid >> 3);
    const int bm0 = (swz / nbx) << 8;
    const int bn0 = (swz % nbx) << 8;

    const int tid  = threadIdx.x;
    const int lane = tid & 63;
    const int w    = tid >> 6;                   // 0..7
    const int wm   = w >> 2, wn = w & 3;         // 2x4 wave grid
    const int l15  = lane & 15, lhi = lane >> 4;
    const int nt   = K >> 6;

    // staging geometry: thread owns linear LDS slot tid*16 within each 8KB
    // pass-region => row r64 = tid>>3, phys chunk tid&7; swizzled global
    // source chunk = (tid&7) ^ (r64&7).
    const int r64 = tid >> 3;
    const int cg8 = ((tid & 7) ^ (r64 & 7)) << 3;    // source col (elems)

    const __hip_bfloat16* Ab = (const __hip_bfloat16*)Av;
    const float*          Af = (const float*)Av;

    auto stageB = [&](int buf, int kt) {
#pragma unroll
        for (int hh = 0; hh < 2; ++hh)
#pragma unroll
            for (int i = 0; i < 2; ++i) {
                const __hip_bfloat16* g =
                    Bt + (size_t)(bn0 + hh * 128 + i * 64 + r64) * ldb + kt + cg8;
                char* l = smem + buf * 65536 + 32768 + hh * 16384 + i * 8192
                          + w * 1024;            // wave-uniform; HW adds lane*16
                __builtin_amdgcn_global_load_lds(
                    (const __attribute__((address_space(1))) unsigned int*)g,
                    (__attribute__((address_space(3))) unsigned int*)l, 16, 0, 0);
            }
    };
    auto stageA_lds = [&](int buf, int kt) {     // bf16 A via gload_lds
#pragma unroll
        for (int hh = 0; hh < 2; ++hh)
#pragma unroll
            for (int i = 0; i < 2; ++i) {
                const __hip_bfloat16* g =
                    Ab + (size_t)(bm0 + hh * 128 + i * 64 + r64) * lda + kt + cg8;
                char* l = smem + buf * 65536 + hh * 16384 + i * 8192 + w * 1024;
                __builtin_amdgcn_global_load_lds(
                    (const __attribute__((address_space(1))) unsigned int*)g,
                    (__attribute__((address_space(3))) unsigned int*)l, 16, 0, 0);
            }
    };

    float4 areg[4][2];                           // f32 A in flight (AF32)
    auto loadA = [&](int kt) {
#pragma unroll
        for (int p = 0; p < 4; ++p) {            // p = hh*2 + i
            const int hh = p >> 1, i = p & 1;
            const float* g = Af + (size_t)(bm0 + hh * 128 + i * 64 + r64) * lda
                             + kt + cg8;
            areg[p][0] = *(const float4*)g;
            areg[p][1] = *(const float4*)(g + 4);
        }
    };
    auto writeA = [&](int buf) {                 // compiler auto-waits areg deps
#pragma unroll
        for (int p = 0; p < 4; ++p) {
            const int hh = p >> 1, i = p & 1;
            union { unsigned short s[8]; short8 v; } o;
            const float* f0 = (const float*)&areg[p][0];
            const float* f1 = (const float*)&areg[p][1];
#pragma unroll
            for (int k2 = 0; k2 < 4; ++k2) {
                o.s[k2]     = f2bf(f0[k2]);
                o.s[4 + k2] = f2bf(f1[k2]);
            }
            *(short8*)(smem + buf * 65536 + hh * 16384 + i * 8192 + tid * 16) = o.v;
        }
    };

    f32x4 acc[8][4] = {};

    // ---- prologue: tile 0 ----
    stageB(0, 0);
    if (AF32) { loadA(0); writeA(0); }
    else      { stageA_lds(0, 0); }
    asm volatile("s_waitcnt vmcnt(0) lgkmcnt(0)" ::: "memory");
    __builtin_amdgcn_s_barrier();

    for (int t = 0; t < nt; ++t) {
        const int cur = t & 1;
        const bool pf = (t + 1 < nt);
        const int kt1 = (t + 1) << 6;

        const char* sA = smem + cur * 65536;
        const char* sB = sA + 32768;

        // stage A for t+1 early: long-latency loads fly under both mh halves
        if (pf) { if (AF32) loadA(kt1); else stageA_lds(cur ^ 1, kt1); }

#pragma unroll
        for (int mh = 0; mh < 2; ++mh) {
            short8 af[4][2];                 // this mh's A fragments, read ONCE
#pragma unroll
            for (int mi = 0; mi < 4; ++mi) {
                const int r = wm * 128 + mh * 64 + mi * 16 + l15;
#pragma unroll
                for (int kk = 0; kk < 2; ++kk) {
                    const int pc = (kk * 4 + lhi) ^ (r & 7);
                    af[mi][kk] = *(const short8*)(sA + r * 128 + (pc << 4));
                }
            }
            if (mh == 0 && pf) stageB(cur ^ 1, kt1);   // B staged mid-tile
#pragma unroll
            for (int nh = 0; nh < 2; ++nh) {
                short8 bfv[2][2];
#pragma unroll
                for (int ni = 0; ni < 2; ++ni) {
                    const int r = wn * 64 + nh * 32 + ni * 16 + l15;
#pragma unroll
                    for (int kk = 0; kk < 2; ++kk) {
                        const int pc = (kk * 4 + lhi) ^ (r & 7);
                        bfv[ni][kk] = *(const short8*)(sB + r * 128 + (pc << 4));
                    }
                }
#pragma unroll
                for (int mi = 0; mi < 4; ++mi)
#pragma unroll
                    for (int ni = 0; ni < 2; ++ni)
#pragma unroll
                        for (int kk = 0; kk < 2; ++kk)
                            acc[mh * 4 + mi][nh * 2 + ni] =
                                __builtin_amdgcn_mfma_f32_16x16x32_bf16(
                                    af[mi][kk], bfv[ni][kk],
                                    acc[mh * 4 + mi][nh * 2 + ni], 0, 0, 0);
            }
        }

        if (pf) {
            if (AF32) writeA(cur ^ 1);       // cvt+ds_write (auto reg-dep wait)
            // LDS-visibility: drain gloads (issued >=1 mh-half ago) + ds_writes
            asm volatile("s_waitcnt vmcnt(0) lgkmcnt(0)" ::: "memory");
            __builtin_amdgcn_s_barrier();
        }
    }

    // ---- epilogue ----
    float bv[4];
#pragma unroll
    for (int N = 0; N < 4; ++N)
        bv[N] = bias[bn0 + wn * 64 + (N >> 1) * 32 + (N & 1) * 16 + l15];

#pragma unroll
    for (int M = 0; M < 8; ++M)
#pragma unroll
        for (int N = 0; N < 4; ++N)
#pragma unroll
            for (int reg = 0; reg < 4; ++reg) {
                int row = bm0 + wm * 128 + (M >> 2) * 64 + (M & 3) * 16
                          + lhi * 4 + reg;
                int col = bn0 + wn * 64 + (N >> 1) * 32 + (N & 1) * 16 + l15;
                float v = acc[M][N][reg] + bv[N];
                if (BF16OUT)
                    ((__hip_bfloat16*)Cv)[(size_t)row * ldc + col] = __float2bfloat16(v);
                else
                    ((float*)Cv)[(size_t)row * ldc + col] = v;
            }
}

// ---------------------------------------------------------------------------
// WV transpose: wvq[b][t][0:512] (stride 1024) -> wvt[b][d][t]
// ---------------------------------------------------------------------------
__global__ __launch_bounds__(256) void transpose_wv(
    const unsigned short* __restrict__ wvq,
    unsigned short* __restrict__ wvt)
{
    __shared__ unsigned short tl[64][66];
    const int tx  = blockIdx.x;
    const int dx  = blockIdx.y;
    const int b   = blockIdx.z;
    const int tid = threadIdx.x;
    const int r   = tid >> 3;
    const int c8  = (tid & 7) * 8;
    const size_t bbase = (size_t)b << 12;

#pragma unroll
    for (int it = 0; it < 2; ++it) {
        int row = r + it * 32;
        uint4 v = *(const uint4*)(wvq + ((bbase + tx * 64 + row) << 10) + dx * 64 + c8);
        *(unsigned*)&tl[row][c8 + 0] = v.x;
        *(unsigned*)&tl[row][c8 + 2] = v.y;
        *(unsigned*)&tl[row][c8 + 4] = v.z;
        *(unsigned*)&tl[row][c8 + 6] = v.w;
    }
    __syncthreads();
#pragma unroll
    for (int it = 0; it < 2; ++it) {
        int drow = r + it * 32;
        union { unsigned short s[8]; uint4 v; } o;
#pragma unroll
        for (int k = 0; k < 8; ++k) o.s[k] = tl[c8 + k][drow];
        *(uint4*)(wvt + (((size_t)b * 512 + dx * 64 + drow) << 12) + tx * 64 + c8) = o.v;
    }
}

// ---------------------------------------------------------------------------
// MFMA windowed attention. Block = 64 tokens, 4 waves.
// ---------------------------------------------------------------------------
__global__ __launch_bounds__(256) void attn_mfma(
    const __hip_bfloat16* __restrict__ WVQ,   // [32768][1024]: 0:512=WV, 512:=Q
    const __hip_bfloat16* __restrict__ WVT,   // [8][512][4096]
    __hip_bfloat16* __restrict__ R)           // [32768][512]
{
    __shared__ __align__(16) unsigned short p_lds[64][136];  // 17408 B

    const int blk = blockIdx.x;
    const int b   = blk >> 6;
    const int t0  = (blk & 63) << 6;
    const int jmin = (t0 == 0) ? 64 : 0;
    const size_t bbase = (size_t)b << 12;
    const int tid  = threadIdx.x;
    const int lane = tid & 63;
    const int w    = tid >> 6;
    const int l15  = lane & 15;
    const int lhi  = lane >> 4;

    // ---- QK^T:  S[64][128] ----
    f32x4 acc[8] = {};
    const __hip_bfloat16* q0 =
        WVQ + ((bbase + t0 + w * 16 + l15) << 10) + 512 + lhi * 8;

    const __hip_bfloat16* brow[8];
#pragma unroll
    for (int nt = 0; nt < 8; ++nt) {
        int aj = t0 - 64 + nt * 16 + l15;
        if (aj < 0) aj = 0;                 // clamped; masked below
        brow[nt] = WVQ + ((bbase + aj) << 10) + lhi * 8;
    }

    for (int kt = 0; kt < 16; ++kt) {
        short8 qa = *(const short8*)(q0 + kt * 32);
#pragma unroll
        for (int nt = 0; nt < 8; ++nt) {
            short8 bv = *(const short8*)(brow[nt] + kt * 32);
            acc[nt] = __builtin_amdgcn_mfma_f32_16x16x32_bf16(qa, bv, acc[nt], 0, 0, 0);
        }
    }

    // ---- wave-local softmax ----
    float m4[4] = { -1e30f, -1e30f, -1e30f, -1e30f };
#pragma unroll
    for (int nt = 0; nt < 8; ++nt)
#pragma unroll
        for (int reg = 0; reg < 4; ++reg) {
            int i = w * 16 + lhi * 4 + reg;
            int j = nt * 16 + l15;
            bool valid = (j >= i) && (j <= i + 63) && (j >= jmin);
            float s = valid ? acc[nt][reg] * SCALE_F : -1e30f;
            acc[nt][reg] = s;
            m4[reg] = fmaxf(m4[reg], s);
        }
#pragma unroll
    for (int off = 8; off >= 1; off >>= 1)
#pragma unroll
        for (int reg = 0; reg < 4; ++reg)
            m4[reg] = fmaxf(m4[reg], __shfl_xor(m4[reg], off, 64));

    float sum4[4] = {};
#pragma unroll
    for (int nt = 0; nt < 8; ++nt)
#pragma unroll
        for (int reg = 0; reg < 4; ++reg) {
            float s = acc[nt][reg];
            float p = (s > -1e29f) ? __expf(s - m4[reg]) : 0.f;
            acc[nt][reg] = p;
            sum4[reg] += p;
        }
#pragma unroll
    for (int off = 8; off >= 1; off >>= 1)
#pragma unroll
        for (int reg = 0; reg < 4; ++reg)
            sum4[reg] += __shfl_xor(sum4[reg], off, 64);

    float rs4[4];
#pragma unroll
    for (int reg = 0; reg < 4; ++reg)
        rs4[reg] = (sum4[reg] > 0.f) ? 1.f / sum4[reg] : 0.f;

#pragma unroll
    for (int nt = 0; nt < 8; ++nt)
#pragma unroll
        for (int reg = 0; reg < 4; ++reg)
            p_lds[w * 16 + lhi * 4 + reg][nt * 16 + l15] =
                f2bf(acc[nt][reg] * rs4[reg]);

    __syncthreads();

    // ---- PV ----
    short8 pa[4];
#pragma unroll
    for (int kt = 0; kt < 4; ++kt)
        pa[kt] = *(const short8*)&p_lds[w * 16 + l15][kt * 32 + lhi * 8];

    int tclamp[4];
#pragma unroll
    for (int kt = 0; kt < 4; ++kt) {
        int ti = t0 - 64 + kt * 32 + lhi * 8;
        tclamp[kt] = ti < 0 ? 0 : ti;       // 8-chunks never straddle 0
    }

    const size_t vbase = (size_t)b * 512;
    for (int nt = 0; nt < 32; ++nt) {
        int d = nt * 16 + l15;
        f32x4 a = {};
#pragma unroll
        for (int kt = 0; kt < 4; ++kt) {
            short8 bv = *(const short8*)(WVT + ((vbase + d) << 12) + tclamp[kt]);
            a = __builtin_amdgcn_mfma_f32_16x16x32_bf16(pa[kt], bv, a, 0, 0, 0);
        }
        size_t rb = (bbase + t0 + w * 16 + lhi * 4) << 9;
#pragma unroll
        for (int reg = 0; reg < 4; ++reg)
            R[rb + ((size_t)reg << 9) + d] = __float2bfloat16(a[reg]);
    }
}

// ---------------------------------------------------------------------------
extern "C" void kernel_launch(void* const* d_in, const int* in_sizes, int n_in,
                              void* d_out, int out_size, void* d_ws, size_t ws_size,
                              hipStream_t stream)
{
    const float* emb   = (const float*)d_in[0];
    const float* W_wr  = (const float*)d_in[1];
    const float* b_wr  = (const float*)d_in[2];
    const float* W_qr  = (const float*)d_in[3];
    const float* b_qr  = (const float*)d_in[4];
    const float* W_out = (const float*)d_in[5];
    const float* b_out = (const float*)d_in[6];
    float* out = (float*)d_out;

    char* ws = (char*)d_ws;
    __hip_bfloat16* wvt  = (__hip_bfloat16*)(ws);                         // 32MB
    __hip_bfloat16* wvq  = (__hip_bfloat16*)(ws + (((size_t)64) << 20));  // 64MB
    __hip_bfloat16* rbuf = (__hip_bfloat16*)(ws + (((size_t)128) << 20)); // 32MB
    __hip_bfloat16* wcat = (__hip_bfloat16*)(ws + (((size_t)160) << 20)); // 2MB
    __hip_bfloat16* wout = (__hip_bfloat16*)(ws + (((size_t)162) << 20)); // 1MB
    float*          bcat = (float*)        (ws + (((size_t)163) << 20));  // 4KB

    tcast<<<dim3(2048), dim3(256), 0, stream>>>(W_wr, wcat, EMB, DM);
    tcast<<<dim3(2048), dim3(256), 0, stream>>>(W_qr, wcat + (size_t)DM * EMB, EMB, DM);
    tcast<<<dim3(2048), dim3(256), 0, stream>>>(W_out, wout, DM, EMB);
    concat_bias<<<dim3(4), dim3(256), 0, stream>>>(b_wr, b_qr, bcat);

    // WVQ = emb(f32) @ wcat^T + bcat   (M=32768, N=1024, K=1024), bf16 out
    gemm256<true, true><<<dim3(512), dim3(512), 0, stream>>>(
        (const void*)emb, EMB, wcat, EMB, bcat, (void*)wvq, 1024, EMB, 4);

    transpose_wv<<<dim3(64, 8, 8), dim3(256), 0, stream>>>(
        (const unsigned short*)wvq, (unsigned short*)wvt);

    attn_mfma<<<dim3(MROWS / 64), dim3(256), 0, stream>>>(wvq, wvt, rbuf);

    // out = rbuf @ wout^T + b_out  (M=32768, N=1024, K=512), f32 out
    gemm256<false, false><<<dim3(512), dim3(512), 0, stream>>>(
        (const void*)rbuf, DM, wout, DM, b_out, (void*)out, EMB, DM, 4);
}

// Round 11
// 238.182 us; speedup vs baseline: 1.0293x; 1.0293x over previous
//
#include <hip/hip_runtime.h>
#include <hip/hip_bf16.h>
#include <math.h>

// HashMemory: B=8, S=4096, E=1024, Dm=512, M=64 slots.
// memory at step t == write_vals of tokens [t-64, t-1]  => window-64 attention.
// Pipeline: prep (emb cast + weight transposes + biases, ONE kernel);
// WVQ = embb @ [W_write|W_query] (256^2 MFMA GEMM); WVT = WV^T;
// windowed attention (MFMA QK^T + wave-local softmax + MFMA PV);
// out = R @ W_out (256^2 MFMA GEMM, f32 out).
// r11: GEMM fragment dedup — B-frags read ONCE per tile (held in regs),
// A-frags once per mh: 24 ds_read_b128/wave/tile (was 48 in r8, 32 in r10),
// putting MFMA (not LDS) on the critical path. A staged via global_load_lds
// (bf16, fused-f32-cast reverted — it cost ~25us inside GEMM in r9/r10).

#define BATCH   8
#define S_LEN   4096
#define EMB     1024
#define DM      512
#define MROWS   (BATCH * S_LEN)          // 32768
#define SCALE_F 0.04419417382415922f     // 512^-0.5

typedef __attribute__((ext_vector_type(4))) float f32x4;
typedef __attribute__((ext_vector_type(8))) short short8;

__device__ __forceinline__ unsigned short f2bf(float f) {
    __hip_bfloat16 h = __float2bfloat16(f);
    return *reinterpret_cast<unsigned short*>(&h);
}

// ---------------------------------------------------------------------------
// Fused prep: emb f32->bf16 cast (blocks 0..32767), W_wr/W_qr/W_out
// transpose+cast (blocks 32768..38911), bias concat (block 38912).
// ---------------------------------------------------------------------------
__global__ __launch_bounds__(256) void prep(
    const float4* __restrict__ emb4, ushort4* __restrict__ embb4,
    const float* __restrict__ W_wr, const float* __restrict__ W_qr,
    const float* __restrict__ W_out,
    const float* __restrict__ b_wr, const float* __restrict__ b_qr,
    __hip_bfloat16* __restrict__ wcat, __hip_bfloat16* __restrict__ wout,
    float* __restrict__ bcat)
{
    const int bx = blockIdx.x;
    if (bx < 32768) {                              // emb cast: 8M float4
        int id = bx * 256 + threadIdx.x;
        float4 v = emb4[id];
        ushort4 o;
        o.x = f2bf(v.x); o.y = f2bf(v.y); o.z = f2bf(v.z); o.w = f2bf(v.w);
        embb4[id] = o;
    } else if (bx < 32768 + 2048) {                // wcat[0:512][1024] = W_wr^T
        int id = (bx - 32768) * 256 + threadIdx.x;
        int n = id >> 10, k = id & 1023;
        wcat[id] = __float2bfloat16(W_wr[k * 512 + n]);
    } else if (bx < 32768 + 4096) {                // wcat[512:1024][1024] = W_qr^T
        int id = (bx - 32768 - 2048) * 256 + threadIdx.x;
        int n = id >> 10, k = id & 1023;
        wcat[(size_t)DM * EMB + id] = __float2bfloat16(W_qr[k * 512 + n]);
    } else if (bx < 32768 + 6144) {                // wout[1024][512] = W_out^T
        int id = (bx - 32768 - 4096) * 256 + threadIdx.x;
        int n = id >> 9, k = id & 511;
        wout[id] = __float2bfloat16(W_out[k * 1024 + n]);
    } else {                                       // bias concat
        int i = threadIdx.x;
#pragma unroll
        for (int r = 0; r < 4; ++r, i += 256)
            bcat[i] = (i < 512) ? b_wr[i] : b_qr[i - 512];
    }
}

// ---------------------------------------------------------------------------
// bf16 MFMA GEMM, 256x256 tile: C[M x N] = A[M x K] @ Bt[N x K]^T + bias.
// 512 threads = 8 waves (2x4); per-wave output 128x64; BK=64.
// LDS: [buf][A 32K | B 32K] x2 = 128KB. Rows 128B, chunk swizzle ^(row&7).
// Per K-tile: stage all 8 gloads at top (full tile of latency cover),
// B-frags read once into regs, A-frags once per mh, 64 MFMA, 1 barrier.
// ---------------------------------------------------------------------------
template<bool BF16OUT>
__global__ __launch_bounds__(512, 2) void gemm256(
    const __hip_bfloat16* __restrict__ A, int lda,
    const __hip_bfloat16* __restrict__ Bt, int ldb,
    const float* __restrict__ bias,
    void* __restrict__ Cv, int ldc,
    int K, int nbx)
{
    __shared__ __align__(16) char smem[131072];

    const int nwg = gridDim.x;
    const int bid = blockIdx.x;
    const int cpx = nwg >> 3;                    // nwg divisible by 8
    const int swz = (bid & 7) * cpx + (bid >> 3);
    const int bm0 = (swz / nbx) << 8;
    const int bn0 = (swz % nbx) << 8;

    const int tid  = threadIdx.x;
    const int lane = tid & 63;
    const int w    = tid >> 6;                   // 0..7
    const int wm   = w >> 2, wn = w & 3;         // 2x4 wave grid
    const int l15  = lane & 15, lhi = lane >> 4;
    const int nt   = K >> 6;

    // staging geometry: thread owns linear LDS slot tid*16 per 8KB region
    // => row r64 = tid>>3, phys chunk tid&7; source chunk = (tid&7)^(r64&7).
    const int r64 = tid >> 3;
    const int cg8 = ((tid & 7) ^ (r64 & 7)) << 3;

    auto stage_tile = [&](int buf, int kt) {     // all 8 gloads, issued first
#pragma unroll
        for (int h = 0; h < 4; ++h) {            // 0=A0 1=A1 2=B0 3=B1
            const int isB = h >> 1, hh = h & 1;
            const __hip_bfloat16* G = isB ? Bt : A;
            const int ldg = isB ? ldb : lda;
            const int rb  = (isB ? bn0 : bm0) + hh * 128;
#pragma unroll
            for (int i = 0; i < 2; ++i) {
                const __hip_bfloat16* g =
                    G + (size_t)(rb + i * 64 + r64) * ldg + kt + cg8;
                char* l = smem + buf * 65536 + isB * 32768 + hh * 16384
                          + i * 8192 + w * 1024;   // wave-uniform; HW adds lane*16
                __builtin_amdgcn_global_load_lds(
                    (const __attribute__((address_space(1))) unsigned int*)g,
                    (__attribute__((address_space(3))) unsigned int*)l, 16, 0, 0);
            }
        }
    };

    f32x4 acc[8][4] = {};   // [mh*4+mi][nh*2+ni]

    stage_tile(0, 0);
    __syncthreads();

    for (int t = 0; t < nt; ++t) {
        const int cur = t & 1;
        const bool pf = (t + 1 < nt);
        if (pf) stage_tile(cur ^ 1, (t + 1) << 6);   // fly under whole tile

        const char* sA = smem + cur * 65536;
        const char* sB = sA + 32768;

        // ---- B fragments: read ONCE per tile (8 reads, held in regs) ----
        short8 bfv[2][2][2];                     // [nh][ni][kk]
#pragma unroll
        for (int nh = 0; nh < 2; ++nh)
#pragma unroll
            for (int ni = 0; ni < 2; ++ni) {
                const int r = wn * 64 + nh * 32 + ni * 16 + l15;
#pragma unroll
                for (int kk = 0; kk < 2; ++kk) {
                    const int pc = (kk * 4 + lhi) ^ (r & 7);
                    bfv[nh][ni][kk] = *(const short8*)(sB + r * 128 + (pc << 4));
                }
            }

        // ---- A fragments once per mh; 32 MFMA per mh ----
#pragma unroll
        for (int mh = 0; mh < 2; ++mh) {
            short8 af[4][2];
#pragma unroll
            for (int mi = 0; mi < 4; ++mi) {
                const int r = wm * 128 + mh * 64 + mi * 16 + l15;
#pragma unroll
                for (int kk = 0; kk < 2; ++kk) {
                    const int pc = (kk * 4 + lhi) ^ (r & 7);
                    af[mi][kk] = *(const short8*)(sA + r * 128 + (pc << 4));
                }
            }
#pragma unroll
            for (int nh = 0; nh < 2; ++nh)
#pragma unroll
                for (int mi = 0; mi < 4; ++mi)
#pragma unroll
                    for (int ni = 0; ni < 2; ++ni)
#pragma unroll
                        for (int kk = 0; kk < 2; ++kk)
                            acc[mh * 4 + mi][nh * 2 + ni] =
                                __builtin_amdgcn_mfma_f32_16x16x32_bf16(
                                    af[mi][kk], bfv[nh][ni][kk],
                                    acc[mh * 4 + mi][nh * 2 + ni], 0, 0, 0);
        }

        if (pf) __syncthreads();   // drains next-tile stages; swap buffers
    }

    // ---- epilogue ----
    float bv[4];
#pragma unroll
    for (int N = 0; N < 4; ++N)
        bv[N] = bias[bn0 + wn * 64 + (N >> 1) * 32 + (N & 1) * 16 + l15];

#pragma unroll
    for (int M = 0; M < 8; ++M)
#pragma unroll
        for (int N = 0; N < 4; ++N)
#pragma unroll
            for (int reg = 0; reg < 4; ++reg) {
                int row = bm0 + wm * 128 + (M >> 2) * 64 + (M & 3) * 16
                          + lhi * 4 + reg;
                int col = bn0 + wn * 64 + (N >> 1) * 32 + (N & 1) * 16 + l15;
                float v = acc[M][N][reg] + bv[N];
                if (BF16OUT)
                    ((__hip_bfloat16*)Cv)[(size_t)row * ldc + col] = __float2bfloat16(v);
                else
                    ((float*)Cv)[(size_t)row * ldc + col] = v;
            }
}

// ---------------------------------------------------------------------------
// WV transpose: wvq[b][t][0:512] (stride 1024) -> wvt[b][d][t]
// ---------------------------------------------------------------------------
__global__ __launch_bounds__(256) void transpose_wv(
    const unsigned short* __restrict__ wvq,
    unsigned short* __restrict__ wvt)
{
    __shared__ unsigned short tl[64][66];
    const int tx  = blockIdx.x;
    const int dx  = blockIdx.y;
    const int b   = blockIdx.z;
    const int tid = threadIdx.x;
    const int r   = tid >> 3;
    const int c8  = (tid & 7) * 8;
    const size_t bbase = (size_t)b << 12;

#pragma unroll
    for (int it = 0; it < 2; ++it) {
        int row = r + it * 32;
        uint4 v = *(const uint4*)(wvq + ((bbase + tx * 64 + row) << 10) + dx * 64 + c8);
        *(unsigned*)&tl[row][c8 + 0] = v.x;
        *(unsigned*)&tl[row][c8 + 2] = v.y;
        *(unsigned*)&tl[row][c8 + 4] = v.z;
        *(unsigned*)&tl[row][c8 + 6] = v.w;
    }
    __syncthreads();
#pragma unroll
    for (int it = 0; it < 2; ++it) {
        int drow = r + it * 32;
        union { unsigned short s[8]; uint4 v; } o;
#pragma unroll
        for (int k = 0; k < 8; ++k) o.s[k] = tl[c8 + k][drow];
        *(uint4*)(wvt + (((size_t)b * 512 + dx * 64 + drow) << 12) + tx * 64 + c8) = o.v;
    }
}

// ---------------------------------------------------------------------------
// MFMA windowed attention. Block = 64 tokens, 4 waves.
// ---------------------------------------------------------------------------
__global__ __launch_bounds__(256) void attn_mfma(
    const __hip_bfloat16* __restrict__ WVQ,   // [32768][1024]: 0:512=WV, 512:=Q
    const __hip_bfloat16* __restrict__ WVT,   // [8][512][4096]
    __hip_bfloat16* __restrict__ R)           // [32768][512]
{
    __shared__ __align__(16) unsigned short p_lds[64][136];  // 17408 B

    const int blk = blockIdx.x;
    const int b   = blk >> 6;
    const int t0  = (blk & 63) << 6;
    const int jmin = (t0 == 0) ? 64 : 0;
    const size_t bbase = (size_t)b << 12;
    const int tid  = threadIdx.x;
    const int lane = tid & 63;
    const int w    = tid >> 6;
    const int l15  = lane & 15;
    const int lhi  = lane >> 4;

    // ---- QK^T:  S[64][128] ----
    f32x4 acc[8] = {};
    const __hip_bfloat16* q0 =
        WVQ + ((bbase + t0 + w * 16 + l15) << 10) + 512 + lhi * 8;

    const __hip_bfloat16* brow[8];
#pragma unroll
    for (int nt = 0; nt < 8; ++nt) {
        int aj = t0 - 64 + nt * 16 + l15;
        if (aj < 0) aj = 0;                 // clamped; masked below
        brow[nt] = WVQ + ((bbase + aj) << 10) + lhi * 8;
    }

#pragma unroll 2
    for (int kt = 0; kt < 16; ++kt) {
        short8 qa = *(const short8*)(q0 + kt * 32);
#pragma unroll
        for (int nt = 0; nt < 8; ++nt) {
            short8 bv = *(const short8*)(brow[nt] + kt * 32);
            acc[nt] = __builtin_amdgcn_mfma_f32_16x16x32_bf16(qa, bv, acc[nt], 0, 0, 0);
        }
    }

    // ---- wave-local softmax ----
    float m4[4] = { -1e30f, -1e30f, -1e30f, -1e30f };
#pragma unroll
    for (int nt = 0; nt < 8; ++nt)
#pragma unroll
        for (int reg = 0; reg < 4; ++reg) {
            int i = w * 16 + lhi * 4 + reg;
            int j = nt * 16 + l15;
            bool valid = (j >= i) && (j <= i + 63) && (j >= jmin);
            float s = valid ? acc[nt][reg] * SCALE_F : -1e30f;
            acc[nt][reg] = s;
            m4[reg] = fmaxf(m4[reg], s);
        }
#pragma unroll
    for (int off = 8; off >= 1; off >>= 1)
#pragma unroll
        for (int reg = 0; reg < 4; ++reg)
            m4[reg] = fmaxf(m4[reg], __shfl_xor(m4[reg], off, 64));

    float sum4[4] = {};
#pragma unroll
    for (int nt = 0; nt < 8; ++nt)
#pragma unroll
        for (int reg = 0; reg < 4; ++reg) {
            float s = acc[nt][reg];
            float p = (s > -1e29f) ? __expf(s - m4[reg]) : 0.f;
            acc[nt][reg] = p;
            sum4[reg] += p;
        }
#pragma unroll
    for (int off = 8; off >= 1; off >>= 1)
#pragma unroll
        for (int reg = 0; reg < 4; ++reg)
            sum4[reg] += __shfl_xor(sum4[reg], off, 64);

    float rs4[4];
#pragma unroll
    for (int reg = 0; reg < 4; ++reg)
        rs4[reg] = (sum4[reg] > 0.f) ? 1.f / sum4[reg] : 0.f;

#pragma unroll
    for (int nt = 0; nt < 8; ++nt)
#pragma unroll
        for (int reg = 0; reg < 4; ++reg)
            p_lds[w * 16 + lhi * 4 + reg][nt * 16 + l15] =
                f2bf(acc[nt][reg] * rs4[reg]);

    __syncthreads();

    // ---- PV ----
    short8 pa[4];
#pragma unroll
    for (int kt = 0; kt < 4; ++kt)
        pa[kt] = *(const short8*)&p_lds[w * 16 + l15][kt * 32 + lhi * 8];

    int tclamp[4];
#pragma unroll
    for (int kt = 0; kt < 4; ++kt) {
        int ti = t0 - 64 + kt * 32 + lhi * 8;
        tclamp[kt] = ti < 0 ? 0 : ti;       // 8-chunks never straddle 0
    }

    const size_t vbase = (size_t)b * 512;
#pragma unroll 2
    for (int nt = 0; nt < 32; ++nt) {
        int d = nt * 16 + l15;
        f32x4 a = {};
#pragma unroll
        for (int kt = 0; kt < 4; ++kt) {
            short8 bv = *(const short8*)(WVT + ((vbase + d) << 12) + tclamp[kt]);
            a = __builtin_amdgcn_mfma_f32_16x16x32_bf16(pa[kt], bv, a, 0, 0, 0);
        }
        size_t rb = (bbase + t0 + w * 16 + lhi * 4) << 9;
#pragma unroll
        for (int reg = 0; reg < 4; ++reg)
            R[rb + ((size_t)reg << 9) + d] = __float2bfloat16(a[reg]);
    }
}

// ---------------------------------------------------------------------------
extern "C" void kernel_launch(void* const* d_in, const int* in_sizes, int n_in,
                              void* d_out, int out_size, void* d_ws, size_t ws_size,
                              hipStream_t stream)
{
    const float* emb   = (const float*)d_in[0];
    const float* W_wr  = (const float*)d_in[1];
    const float* b_wr  = (const float*)d_in[2];
    const float* W_qr  = (const float*)d_in[3];
    const float* b_qr  = (const float*)d_in[4];
    const float* W_out = (const float*)d_in[5];
    const float* b_out = (const float*)d_in[6];
    float* out = (float*)d_out;

    char* ws = (char*)d_ws;
    __hip_bfloat16* embb = (__hip_bfloat16*)(ws);                         // 64MB (dead after gemm1)
    __hip_bfloat16* wvt  = (__hip_bfloat16*)(ws);                         // 32MB, aliases embb
    __hip_bfloat16* wvq  = (__hip_bfloat16*)(ws + (((size_t)64) << 20));  // 64MB
    __hip_bfloat16* rbuf = (__hip_bfloat16*)(ws + (((size_t)128) << 20)); // 32MB
    __hip_bfloat16* wcat = (__hip_bfloat16*)(ws + (((size_t)160) << 20)); // 2MB
    __hip_bfloat16* wout = (__hip_bfloat16*)(ws + (((size_t)162) << 20)); // 1MB
    float*          bcat = (float*)        (ws + (((size_t)163) << 20));  // 4KB

    // wvt aliases embb: embb consumed by gemm1 BEFORE transpose_wv writes wvt.
    prep<<<dim3(38913), dim3(256), 0, stream>>>(
        (const float4*)emb, (ushort4*)embb,
        W_wr, W_qr, W_out, b_wr, b_qr, wcat, wout, bcat);

    // WVQ = embb @ wcat^T + bcat   (M=32768, N=1024, K=1024), bf16 out
    gemm256<true><<<dim3(512), dim3(512), 0, stream>>>(
        embb, EMB, wcat, EMB, bcat, (void*)wvq, 1024, EMB, 4);

    transpose_wv<<<dim3(64, 8, 8), dim3(256), 0, stream>>>(
        (const unsigned short*)wvq, (unsigned short*)wvt);

    attn_mfma<<<dim3(MROWS / 64), dim3(256), 0, stream>>>(wvq, wvt, rbuf);

    // out = rbuf @ wout^T + b_out  (M=32768, N=1024, K=512), f32 out
    gemm256<false><<<dim3(512), dim3(512), 0, stream>>>(
        rbuf, DM, wout, DM, b_out, (void*)out, EMB, DM, 4);
}